// Round 6
// baseline (173.011 us; speedup 1.0000x reference)
//
#include <hip/hip_runtime.h>

#define VR 4
#define NVOX 64            // VR^3
#define NCLS 40
#define NB 64
#define NPTS 100000
#define G_TOT 25000        // 4-point groups per batch (3 float4 each)
#define F4_PER_B 75000     // float4 per batch
#define TPB 1024           // 16 waves
#define FULL_ITERS 6       // 6 * 4096 groups = 24576
#define TAIL 424           // 25000 - 24576
#define FLT_BIG 3.402823466e38f

__device__ __forceinline__ int bin1(float v, float mn, float s4) {
    int i = (int)((v - mn) * s4);   // v>=mn, s4>0 -> trunc==floor
    return i > (VR - 1) ? (VR - 1) : i;
}

__device__ __forceinline__ void tally(int v, unsigned long long vm,
                                      const unsigned long long* ns,
                                      unsigned& cnt) {
    unsigned long long b0 = __ballot(v & 1);
    unsigned long long b1 = __ballot(v & 2);
    unsigned long long b2 = __ballot(v & 4);
    unsigned long long b3 = __ballot(v & 8);
    unsigned long long b4 = __ballot(v & 16);
    unsigned long long b5 = __ballot(v & 32);
    unsigned long long m = vm & (b0 ^ ns[0]) & (b1 ^ ns[1]) & (b2 ^ ns[2])
                              & (b3 ^ ns[3]) & (b4 ^ ns[4]) & (b5 ^ ns[5]);
    cnt += (unsigned)__popcll(m);
}

// One block per batch: minmax -> __syncthreads -> ballot hist -> GEMV.
// No grid sync, no device-scope fences, no workspace, single dispatch.
__global__ __launch_bounds__(TPB) void fused_k(const float4* __restrict__ x,
                                               const float* __restrict__ W,
                                               const float* __restrict__ bias,
                                               float* __restrict__ out) {
    const int b = blockIdx.x;
    const float4* xb = x + (size_t)b * F4_PER_B;
    const int tid = threadIdx.x;
    const int lane = tid & 63;
    const int wv = tid >> 6;

    __shared__ float sW[NCLS * 65];          // pad 64->65: kills 40-way bank conflict
    __shared__ float smn[16][3], smx[16][3];
    __shared__ float smm[6];                 // mn0 mn1 mn2 mx0 mx1 mx2
    __shared__ unsigned swh[16][NVOX];
    __shared__ float fh[NVOX];

    // stage W (10 KB, L3-cold but tiny) while phase-A loads run
    for (int i = tid; i < NCLS * NVOX; i += TPB)
        sW[(i >> 6) * 65 + (i & 63)] = W[i];

    // ---------------- phase A: min/max over this batch ----------------------
    float mn0 = FLT_BIG, mn1 = FLT_BIG, mn2 = FLT_BIG;
    float mx0 = -FLT_BIG, mx1 = -FLT_BIG, mx2 = -FLT_BIG;

    for (int it = 0; it < FULL_ITERS; ++it) {
        float4 d[12];
        #pragma unroll
        for (int k = 0; k < 4; ++k) {
            int g = it * (4 * TPB) + k * TPB + tid;
            d[3 * k + 0] = xb[3 * g + 0];
            d[3 * k + 1] = xb[3 * g + 1];
            d[3 * k + 2] = xb[3 * g + 2];
        }
        #pragma unroll
        for (int k = 0; k < 4; ++k) {
            float4 a = d[3 * k], c = d[3 * k + 1], e = d[3 * k + 2];
            // flat%3: a.x->0 a.y->1 a.z->2 a.w->0 c.x->1 c.y->2
            //         c.z->0 c.w->1 e.x->2 e.y->0 e.z->1 e.w->2
            mn0 = fminf(mn0, fminf(fminf(a.x, a.w), fminf(c.z, e.y)));
            mx0 = fmaxf(mx0, fmaxf(fmaxf(a.x, a.w), fmaxf(c.z, e.y)));
            mn1 = fminf(mn1, fminf(fminf(a.y, c.x), fminf(c.w, e.z)));
            mx1 = fmaxf(mx1, fmaxf(fmaxf(a.y, c.x), fmaxf(c.w, e.z)));
            mn2 = fminf(mn2, fminf(fminf(a.z, c.y), fminf(e.x, e.w)));
            mx2 = fmaxf(mx2, fmaxf(fmaxf(a.z, c.y), fmaxf(e.x, e.w)));
        }
    }
    if (tid < TAIL) {
        int g = FULL_ITERS * 4 * TPB + tid;
        float4 a = xb[3 * g], c = xb[3 * g + 1], e = xb[3 * g + 2];
        mn0 = fminf(mn0, fminf(fminf(a.x, a.w), fminf(c.z, e.y)));
        mx0 = fmaxf(mx0, fmaxf(fmaxf(a.x, a.w), fmaxf(c.z, e.y)));
        mn1 = fminf(mn1, fminf(fminf(a.y, c.x), fminf(c.w, e.z)));
        mx1 = fmaxf(mx1, fmaxf(fmaxf(a.y, c.x), fmaxf(c.w, e.z)));
        mn2 = fminf(mn2, fminf(fminf(a.z, c.y), fminf(e.x, e.w)));
        mx2 = fmaxf(mx2, fmaxf(fmaxf(a.z, c.y), fmaxf(e.x, e.w)));
    }

    #pragma unroll
    for (int off = 32; off > 0; off >>= 1) {
        mn0 = fminf(mn0, __shfl_down(mn0, off, 64));
        mn1 = fminf(mn1, __shfl_down(mn1, off, 64));
        mn2 = fminf(mn2, __shfl_down(mn2, off, 64));
        mx0 = fmaxf(mx0, __shfl_down(mx0, off, 64));
        mx1 = fmaxf(mx1, __shfl_down(mx1, off, 64));
        mx2 = fmaxf(mx2, __shfl_down(mx2, off, 64));
    }
    if (lane == 0) {
        smn[wv][0] = mn0; smn[wv][1] = mn1; smn[wv][2] = mn2;
        smx[wv][0] = mx0; smx[wv][1] = mx1; smx[wv][2] = mx2;
    }
    __syncthreads();
    if (tid < 3) {
        float a = smn[0][tid], z = smx[0][tid];
        #pragma unroll
        for (int w = 1; w < 16; w++) {
            a = fminf(a, smn[w][tid]);
            z = fmaxf(z, smx[w][tid]);
        }
        smm[tid] = a;
        smm[3 + tid] = z;
    }
    __syncthreads();

    const float mn_0 = smm[0], mn_1 = smm[1], mn_2 = smm[2];
    const float s4_0 = (float)VR / (smm[3] - mn_0);
    const float s4_1 = (float)VR / (smm[4] - mn_1);
    const float s4_2 = (float)VR / (smm[5] - mn_2);

    // ---------------- phase B: ballot histogram (x now L3/L2-resident) ------
    unsigned long long ns[6];
    #pragma unroll
    for (int k = 0; k < 6; k++)
        ns[k] = ((lane >> k) & 1) ? 0ull : ~0ull;

    unsigned c_ = 0;
    for (int it = 0; it < FULL_ITERS; ++it) {
        float4 d[12];
        #pragma unroll
        for (int k = 0; k < 4; ++k) {
            int g = it * (4 * TPB) + k * TPB + tid;
            d[3 * k + 0] = xb[3 * g + 0];
            d[3 * k + 1] = xb[3 * g + 1];
            d[3 * k + 2] = xb[3 * g + 2];
        }
        #pragma unroll
        for (int k = 0; k < 4; ++k) {
            float4 a = d[3 * k], c = d[3 * k + 1], e = d[3 * k + 2];
            // points: (a.x,a.y,a.z) (a.w,c.x,c.y) (c.z,c.w,e.x) (e.y,e.z,e.w)
            int v0 = bin1(a.x, mn_0, s4_0) * 16 + bin1(a.y, mn_1, s4_1) * 4 + bin1(a.z, mn_2, s4_2);
            int v1 = bin1(a.w, mn_0, s4_0) * 16 + bin1(c.x, mn_1, s4_1) * 4 + bin1(c.y, mn_2, s4_2);
            int v2 = bin1(c.z, mn_0, s4_0) * 16 + bin1(c.w, mn_1, s4_1) * 4 + bin1(e.x, mn_2, s4_2);
            int v3 = bin1(e.y, mn_0, s4_0) * 16 + bin1(e.z, mn_1, s4_1) * 4 + bin1(e.w, mn_2, s4_2);
            tally(v0, ~0ull, ns, c_);
            tally(v1, ~0ull, ns, c_);
            tally(v2, ~0ull, ns, c_);
            tally(v3, ~0ull, ns, c_);
        }
    }
    if (wv * 64 < TAIL) {   // waves with at least one tail lane
        bool act = tid < TAIL;
        int g = act ? (FULL_ITERS * 4 * TPB + tid) : (G_TOT - 1);
        float4 a = xb[3 * g], c = xb[3 * g + 1], e = xb[3 * g + 2];
        unsigned long long vm = __ballot(act);
        int v0 = bin1(a.x, mn_0, s4_0) * 16 + bin1(a.y, mn_1, s4_1) * 4 + bin1(a.z, mn_2, s4_2);
        int v1 = bin1(a.w, mn_0, s4_0) * 16 + bin1(c.x, mn_1, s4_1) * 4 + bin1(c.y, mn_2, s4_2);
        int v2 = bin1(c.z, mn_0, s4_0) * 16 + bin1(c.w, mn_1, s4_1) * 4 + bin1(e.x, mn_2, s4_2);
        int v3 = bin1(e.y, mn_0, s4_0) * 16 + bin1(e.z, mn_1, s4_1) * 4 + bin1(e.w, mn_2, s4_2);
        tally(v0, vm, ns, c_);
        tally(v1, vm, ns, c_);
        tally(v2, vm, ns, c_);
        tally(v3, vm, ns, c_);
    }

    swh[wv][lane] = c_;
    __syncthreads();

    // ---------------- phase C: combine + GEMV -------------------------------
    if (tid < NVOX) {
        unsigned s = 0;
        #pragma unroll
        for (int w = 0; w < 16; w++) s += swh[w][tid];
        fh[tid] = (float)s * (1.0f / (float)NPTS);
    }
    __syncthreads();
    if (tid < NCLS) {
        float acc = 0.f;
        #pragma unroll
        for (int f = 0; f < NVOX; f++)
            acc += fh[f] * sW[tid * 65 + f];
        out[b * NCLS + tid] = acc + bias[tid];
    }
}

extern "C" void kernel_launch(void* const* d_in, const int* in_sizes, int n_in,
                              void* d_out, int out_size, void* d_ws, size_t ws_size,
                              hipStream_t stream) {
    const float* x = (const float*)d_in[0];      // (64, 100000, 3) fp32
    const float* W = (const float*)d_in[1];      // (40, 64) fp32
    const float* bias = (const float*)d_in[2];   // (40,) fp32
    float* out = (float*)d_out;                  // (64, 40) fp32

    fused_k<<<NB, TPB, 0, stream>>>((const float4*)x, W, bias, out);
}

// Round 7
// 126.954 us; speedup vs baseline: 1.3628x; 1.3628x over previous
//
#include <hip/hip_runtime.h>

#define VR 4
#define NVOX 64            // VR^3
#define NCLS 40
#define NB 64
#define NPTS 100000
#define BPB 25             // blocks per batch
#define WPB 4              // waves per block
#define GPW 250            // groups per wave (25 blk * 4 waves * 250 = 25000)
#define F4_PER_B 75000     // float4 per batch
#define TAIL_LANES 58      // last iter: 250 - 3*64 = 58 active lanes
#define F4_PER_WAVE 750    // 3 * GPW float4 per wave
#define FLT_BIG 3.402823466e38f

// Coalesced global -> LDS staging (wave-uniform LDS base + lane*16).
__device__ __forceinline__ void gl2lds(const float4* g, float4* l) {
    __builtin_amdgcn_global_load_lds(
        (const __attribute__((address_space(1))) void*)g,
        (__attribute__((address_space(3))) void*)l, 16, 0, 0);
}

__device__ __forceinline__ int bin1(float v, float mn, float s4) {
    int i = (int)((v - mn) * s4);   // v>=mn, s4>0 -> trunc==floor
    return i > (VR - 1) ? (VR - 1) : i;
}

__device__ __forceinline__ void tally(int v, unsigned long long vm,
                                      const unsigned long long* ns,
                                      unsigned& cnt) {
    unsigned long long b0 = __ballot(v & 1);
    unsigned long long b1 = __ballot(v & 2);
    unsigned long long b2 = __ballot(v & 4);
    unsigned long long b3 = __ballot(v & 8);
    unsigned long long b4 = __ballot(v & 16);
    unsigned long long b5 = __ballot(v & 32);
    unsigned long long m = vm & (b0 ^ ns[0]) & (b1 ^ ns[1]) & (b2 ^ ns[2])
                              & (b3 ^ ns[3]) & (b4 ^ ns[4]) & (b5 ^ ns[5]);
    cnt += (unsigned)__popcll(m);
}

// ---------------------------------------------------------------------------
// Pass 1: min/max. Wave-private double-buffered LDS staging, lane-contiguous
// global loads, no block barriers in the hot loop.
// ---------------------------------------------------------------------------
__global__ __launch_bounds__(256) void minmax_k(const float4* __restrict__ x,
                                                float* __restrict__ pmin,
                                                float* __restrict__ pmax) {
    const int b = blockIdx.x / BPB;
    const int sub = blockIdx.x % BPB;
    const float4* xb = x + (size_t)b * F4_PER_B;
    const int tid = threadIdx.x;
    const int lane = tid & 63;
    const int w = tid >> 6;
    const float4* xw = xb + (size_t)(sub * WPB + w) * F4_PER_WAVE;

    __shared__ float4 stage[WPB][2][192];   // 24 KB

    // prologue: issue iter-0 loads
    #pragma unroll
    for (int j = 0; j < 3; ++j)
        gl2lds(xw + j * 64 + lane, &stage[w][0][j * 64]);

    float mn0 = FLT_BIG, mn1 = FLT_BIG, mn2 = FLT_BIG;
    float mx0 = -FLT_BIG, mx1 = -FLT_BIG, mx2 = -FLT_BIG;

    #pragma unroll
    for (int it = 0; it < 4; ++it) {
        const int cur = it & 1;
        if (it < 3) {
            #pragma unroll
            for (int j = 0; j < 3; ++j) {
                int o = (it + 1) * 192 + j * 64 + lane;
                if (o > F4_PER_WAVE - 1) o = F4_PER_WAVE - 1;   // tail clamp
                gl2lds(xw + o, &stage[w][cur ^ 1][j * 64]);
            }
            __builtin_amdgcn_s_waitcnt(0x0f73);   // vmcnt(3): iter-it loads done
        } else {
            __builtin_amdgcn_s_waitcnt(0x0f70);   // vmcnt(0)
        }
        float4 a = stage[w][cur][3 * lane];
        float4 c = stage[w][cur][3 * lane + 1];
        float4 e = stage[w][cur][3 * lane + 2];
        bool act = (it < 3) || (lane < TAIL_LANES);
        if (act) {
            // flat%3: a.x->0 a.y->1 a.z->2 a.w->0 c.x->1 c.y->2
            //         c.z->0 c.w->1 e.x->2 e.y->0 e.z->1 e.w->2
            mn0 = fminf(mn0, fminf(fminf(a.x, a.w), fminf(c.z, e.y)));
            mx0 = fmaxf(mx0, fmaxf(fmaxf(a.x, a.w), fmaxf(c.z, e.y)));
            mn1 = fminf(mn1, fminf(fminf(a.y, c.x), fminf(c.w, e.z)));
            mx1 = fmaxf(mx1, fmaxf(fmaxf(a.y, c.x), fmaxf(c.w, e.z)));
            mn2 = fminf(mn2, fminf(fminf(a.z, c.y), fminf(e.x, e.w)));
            mx2 = fmaxf(mx2, fmaxf(fmaxf(a.z, c.y), fmaxf(e.x, e.w)));
        }
    }

    #pragma unroll
    for (int off = 32; off > 0; off >>= 1) {
        mn0 = fminf(mn0, __shfl_down(mn0, off, 64));
        mn1 = fminf(mn1, __shfl_down(mn1, off, 64));
        mn2 = fminf(mn2, __shfl_down(mn2, off, 64));
        mx0 = fmaxf(mx0, __shfl_down(mx0, off, 64));
        mx1 = fmaxf(mx1, __shfl_down(mx1, off, 64));
        mx2 = fmaxf(mx2, __shfl_down(mx2, off, 64));
    }

    __shared__ float smn[WPB][3], smx[WPB][3];
    if (lane == 0) {
        smn[w][0] = mn0; smn[w][1] = mn1; smn[w][2] = mn2;
        smx[w][0] = mx0; smx[w][1] = mx1; smx[w][2] = mx2;
    }
    __syncthreads();
    if (tid < 3) {
        float a = smn[0][tid], z = smx[0][tid];
        #pragma unroll
        for (int v = 1; v < WPB; v++) {
            a = fminf(a, smn[v][tid]);
            z = fmaxf(z, smx[v][tid]);
        }
        pmin[(b * BPB + sub) * 3 + tid] = a;
        pmax[(b * BPB + sub) * 3 + tid] = z;
    }
}

// ---------------------------------------------------------------------------
// Pass 2: ballot histogram with the same staging. Each wave redundantly
// reduces the 25 min/max partials in-register (shuffles only, no barrier)
// while its iter-0 staging loads are in flight.
// ---------------------------------------------------------------------------
__global__ __launch_bounds__(256) void hist_k(const float4* __restrict__ x,
                                              const float* __restrict__ pmin,
                                              const float* __restrict__ pmax,
                                              unsigned* __restrict__ phist) {
    const int b = blockIdx.x / BPB;
    const int sub = blockIdx.x % BPB;
    const float4* xb = x + (size_t)b * F4_PER_B;
    const int tid = threadIdx.x;
    const int lane = tid & 63;
    const int w = tid >> 6;
    const float4* xw = xb + (size_t)(sub * WPB + w) * F4_PER_WAVE;

    __shared__ float4 stage[WPB][2][192];   // 24 KB

    #pragma unroll
    for (int j = 0; j < 3; ++j)
        gl2lds(xw + j * 64 + lane, &stage[w][0][j * 64]);

    // per-wave reduction of 25 partials: lanes 0..24 carry pmin (min-half),
    // lanes 32..56 carry pmax (max-half); butterfly within 32-halves.
    float v0, v1, v2;
    {
        bool lo = lane < 32;
        int s = lo ? lane : lane - 32;
        if (s < BPB) {
            const float* src = lo ? pmin : pmax;
            v0 = src[(b * BPB + s) * 3 + 0];
            v1 = src[(b * BPB + s) * 3 + 1];
            v2 = src[(b * BPB + s) * 3 + 2];
        } else {
            v0 = v1 = v2 = lo ? FLT_BIG : -FLT_BIG;
        }
        #pragma unroll
        for (int off = 16; off > 0; off >>= 1) {
            float u0 = __shfl_xor(v0, off, 64);
            float u1 = __shfl_xor(v1, off, 64);
            float u2 = __shfl_xor(v2, off, 64);
            v0 = lo ? fminf(v0, u0) : fmaxf(v0, u0);
            v1 = lo ? fminf(v1, u1) : fmaxf(v1, u1);
            v2 = lo ? fminf(v2, u2) : fmaxf(v2, u2);
        }
    }
    const float mn_0 = __shfl(v0, 0, 64);
    const float mn_1 = __shfl(v1, 0, 64);
    const float mn_2 = __shfl(v2, 0, 64);
    const float s4_0 = (float)VR / (__shfl(v0, 32, 64) - mn_0);
    const float s4_1 = (float)VR / (__shfl(v1, 32, 64) - mn_1);
    const float s4_2 = (float)VR / (__shfl(v2, 32, 64) - mn_2);

    unsigned long long ns[6];
    #pragma unroll
    for (int k = 0; k < 6; k++)
        ns[k] = ((lane >> k) & 1) ? 0ull : ~0ull;

    unsigned c_ = 0;
    #pragma unroll
    for (int it = 0; it < 4; ++it) {
        const int cur = it & 1;
        if (it < 3) {
            #pragma unroll
            for (int j = 0; j < 3; ++j) {
                int o = (it + 1) * 192 + j * 64 + lane;
                if (o > F4_PER_WAVE - 1) o = F4_PER_WAVE - 1;
                gl2lds(xw + o, &stage[w][cur ^ 1][j * 64]);
            }
            __builtin_amdgcn_s_waitcnt(0x0f73);   // vmcnt(3)
        } else {
            __builtin_amdgcn_s_waitcnt(0x0f70);   // vmcnt(0)
        }
        float4 a = stage[w][cur][3 * lane];
        float4 c = stage[w][cur][3 * lane + 1];
        float4 e = stage[w][cur][3 * lane + 2];
        bool act = (it < 3) || (lane < TAIL_LANES);
        unsigned long long vm = act ? ~0ull : 0ull;
        vm = __ballot(act);
        // points: (a.x,a.y,a.z) (a.w,c.x,c.y) (c.z,c.w,e.x) (e.y,e.z,e.w)
        int p0 = bin1(a.x, mn_0, s4_0) * 16 + bin1(a.y, mn_1, s4_1) * 4 + bin1(a.z, mn_2, s4_2);
        int p1 = bin1(a.w, mn_0, s4_0) * 16 + bin1(c.x, mn_1, s4_1) * 4 + bin1(c.y, mn_2, s4_2);
        int p2 = bin1(c.z, mn_0, s4_0) * 16 + bin1(c.w, mn_1, s4_1) * 4 + bin1(e.x, mn_2, s4_2);
        int p3 = bin1(e.y, mn_0, s4_0) * 16 + bin1(e.z, mn_1, s4_1) * 4 + bin1(e.w, mn_2, s4_2);
        tally(p0, vm, ns, c_);
        tally(p1, vm, ns, c_);
        tally(p2, vm, ns, c_);
        tally(p3, vm, ns, c_);
    }

    __shared__ unsigned swh[WPB][NVOX];
    swh[w][lane] = c_;
    __syncthreads();
    if (tid < NVOX) {
        phist[(b * BPB + sub) * NVOX + tid] =
            swh[0][tid] + swh[1][tid] + swh[2][tid] + swh[3][tid];
    }
}

// ---------------------------------------------------------------------------
// Pass 3: reduce the 25 hist partials per batch + 40x64 GEMV, one block/batch.
// ---------------------------------------------------------------------------
__global__ __launch_bounds__(256) void gemv_k(const unsigned* __restrict__ phist,
                                              const float* __restrict__ W,
                                              const float* __restrict__ bias,
                                              float* __restrict__ out) {
    const int b = blockIdx.x;
    __shared__ float fh[NVOX];
    __shared__ float sW[NCLS * NVOX];

    if (threadIdx.x < NVOX) {
        unsigned s = 0;
        for (int p = 0; p < BPB; p++)
            s += phist[(b * BPB + p) * NVOX + threadIdx.x];
        fh[threadIdx.x] = (float)s * (1.0f / (float)NPTS);
    }
    for (int i = threadIdx.x; i < NCLS * NVOX; i += 256)
        sW[i] = W[i];
    __syncthreads();

    if (threadIdx.x < NCLS) {
        const int c = threadIdx.x;
        float acc = 0.f;
        #pragma unroll
        for (int f = 0; f < NVOX; f++)
            acc += fh[f] * sW[c * NVOX + f];
        out[b * NCLS + c] = acc + bias[c];
    }
}

extern "C" void kernel_launch(void* const* d_in, const int* in_sizes, int n_in,
                              void* d_out, int out_size, void* d_ws, size_t ws_size,
                              hipStream_t stream) {
    const float* x = (const float*)d_in[0];      // (64, 100000, 3) fp32
    const float* W = (const float*)d_in[1];      // (40, 64) fp32
    const float* bias = (const float*)d_in[2];   // (40,) fp32
    float* out = (float*)d_out;                  // (64, 40) fp32

    // ws layout (all slots fully overwritten every call -> no init needed):
    //   pmin  : NB*BPB*3 f32
    //   pmax  : NB*BPB*3 f32
    //   phist : NB*BPB*64 u32
    float* pmin = (float*)d_ws;
    float* pmax = pmin + NB * BPB * 3;
    unsigned* phist = (unsigned*)(pmax + NB * BPB * 3);

    minmax_k<<<NB * BPB, 256, 0, stream>>>((const float4*)x, pmin, pmax);
    hist_k<<<NB * BPB, 256, 0, stream>>>((const float4*)x, pmin, pmax, phist);
    gemv_k<<<NB, 256, 0, stream>>>(phist, W, bias, out);
}